// Round 1
// baseline (2771.456 us; speedup 1.0000x reference)
//
#include <hip/hip_runtime.h>

// TT layer: x[256][32][32][32] (fp32), cores (fp32), bias (fp32) -> out fp32.
// Flat layouts:
//   x:     b*32768 + m1*1024 + m2*32 + m3
//   core0: [1][32][32][16]   n1*512 + m1*16 + s
//   core1: [16][32][32][16]  r*16384 + n2*512 + m2*16 + s
//   core2: [16][32][32][1]   r*1024 + n3*32 + m3
//   bias:  n1*1024 + n2*32 + n3
//   out:   b*32768 + n1*1024 + n2*32 + n3
//
// One workgroup per (b, n1): 8192 WGs x 256 threads.
//   Phase A: z1[s][p]  (p = m2*32+m3)   in LDS  (16 x 1028 floats, padded)
//   Phase B: z2[s][n2][m3]              in LDS  (stride s:1156, n2:36 - padded)
//   Phase C: stage core2 transposed (c2t[n3][r*32+m3], stride 516) into z1's
//            region, then y = core2 . z2 + bias.

#define THREADS 256

#define Z1_S   1028   // z1 s-stride (floats)
#define C2T_S  516    // c2t n3-stride (floats)
#define REG_A  16512  // max(16*1028, 32*516)
#define Z2_SS  1156   // z2 s-stride
#define Z2_NS  36     // z2 n2-stride
#define REG_B  18496

__global__ __launch_bounds__(THREADS, 1)
void tt_fused_f32(const float* __restrict__ x,
                  const float* __restrict__ core0,
                  const float* __restrict__ core1,
                  const float* __restrict__ core2,
                  const float* __restrict__ bias,
                  float* __restrict__ out)
{
    __shared__ float smemA[REG_A];  // z1, later c2t
    __shared__ float smemB[REG_B];  // z2

    const int t  = threadIdx.x;
    const int b  = blockIdx.x >> 5;
    const int n1 = blockIdx.x & 31;

    // ---------------- Phase A: z1[s][4t..4t+3] ----------------
    {
        const float4* x4 = (const float4*)x + (size_t)b * 8192 + t;
        const float*  c0 = core0 + n1 * 512;
        float4 acc[16];
        #pragma unroll
        for (int s = 0; s < 16; ++s) acc[s] = make_float4(0.f, 0.f, 0.f, 0.f);
        for (int m1 = 0; m1 < 32; ++m1) {
            float4 xv = x4[m1 * 256];
            #pragma unroll
            for (int s = 0; s < 16; ++s) {
                float c = c0[m1 * 16 + s];   // uniform -> s_load broadcast
                acc[s].x += c * xv.x; acc[s].y += c * xv.y;
                acc[s].z += c * xv.z; acc[s].w += c * xv.w;
            }
        }
        #pragma unroll
        for (int s = 0; s < 16; ++s)
            *(float4*)&smemA[s * Z1_S + 4 * t] = acc[s];
    }
    __syncthreads();

    // ---------------- Phase B: z2[s][n2][m3], n2 in {ng, ng+16} ----------------
    {
        const int s  = t & 15;
        const int ng = t >> 4;
        const float* c1a = core1 + ng * 512 + s;          // + r*16384 + m2*16
        const float* c1b = core1 + (ng + 16) * 512 + s;
        float4 a0[8], a1[8];
        #pragma unroll
        for (int j = 0; j < 8; ++j) {
            a0[j] = make_float4(0.f, 0.f, 0.f, 0.f);
            a1[j] = make_float4(0.f, 0.f, 0.f, 0.f);
        }
        for (int r = 0; r < 16; ++r) {
            const float* rowbase = &smemA[r * Z1_S];
            const float* c1ar = c1a + r * 16384;
            const float* c1br = c1b + r * 16384;
            #pragma unroll 4
            for (int m2 = 0; m2 < 32; ++m2) {
                float ca = c1ar[m2 * 16];
                float cb = c1br[m2 * 16];
                const float4* row4 = (const float4*)(rowbase + m2 * 32);
                #pragma unroll
                for (int j = 0; j < 8; ++j) {
                    float4 v = row4[j];   // broadcast: all lanes same addr
                    a0[j].x += ca * v.x; a0[j].y += ca * v.y;
                    a0[j].z += ca * v.z; a0[j].w += ca * v.w;
                    a1[j].x += cb * v.x; a1[j].y += cb * v.y;
                    a1[j].z += cb * v.z; a1[j].w += cb * v.w;
                }
            }
        }
        #pragma unroll
        for (int j = 0; j < 8; ++j) {
            *(float4*)&smemB[s * Z2_SS + ng * Z2_NS + 4 * j]        = a0[j];
            *(float4*)&smemB[s * Z2_SS + (ng + 16) * Z2_NS + 4 * j] = a1[j];
        }
    }
    __syncthreads();

    // ---------------- Phase C: stage core2 transposed into smemA ----------------
    {
        const float4* c2_4 = (const float4*)core2;
        #pragma unroll
        for (int k = 0; k < 16; ++k) {
            int g4 = t + THREADS * k;          // float4 index
            int e  = 4 * g4;                   // element index
            int r  = e >> 10;
            int n3 = (e >> 5) & 31;
            int m3 = e & 31;
            *(float4*)&smemA[n3 * C2T_S + r * 32 + m3] = c2_4[g4];
        }
    }
    __syncthreads();

    // ---------------- Phase C: y[n2][n3] = sum_{r,m3} c2t[n3][r,m3]*z2[r][n2][m3]
    {
        const int c  = t & 7;        // n3 = 4c + i
        const int n2 = t >> 3;
        float4 acc[4];
        #pragma unroll
        for (int i = 0; i < 4; ++i) acc[i] = make_float4(0.f, 0.f, 0.f, 0.f);
        for (int r = 0; r < 16; ++r) {
            const float4* zrow = (const float4*)&smemB[r * Z2_SS + n2 * Z2_NS];
            #pragma unroll
            for (int j = 0; j < 8; ++j) {
                float4 zv = zrow[j];
                #pragma unroll
                for (int i = 0; i < 4; ++i) {
                    float4 cv = *(const float4*)&smemA[(4 * c + i) * C2T_S + r * 32 + 4 * j];
                    acc[i].x += cv.x * zv.x; acc[i].y += cv.y * zv.y;
                    acc[i].z += cv.z * zv.z; acc[i].w += cv.w * zv.w;
                }
            }
        }
        const int outoff = n2 * 32 + 4 * c;   // within this n1 block
        float4 bv = *(const float4*)&bias[n1 * 1024 + outoff];
        float4 y;
        y.x = acc[0].x + acc[0].y + acc[0].z + acc[0].w + bv.x;
        y.y = acc[1].x + acc[1].y + acc[1].z + acc[1].w + bv.y;
        y.z = acc[2].x + acc[2].y + acc[2].z + acc[2].w + bv.z;
        y.w = acc[3].x + acc[3].y + acc[3].z + acc[3].w + bv.w;
        *(float4*)&out[(size_t)b * 32768 + n1 * 1024 + outoff] = y;
    }
}

extern "C" void kernel_launch(void* const* d_in, const int* in_sizes, int n_in,
                              void* d_out, int out_size, void* d_ws, size_t ws_size,
                              hipStream_t stream) {
    (void)in_sizes; (void)n_in; (void)out_size; (void)d_ws; (void)ws_size;
    const float* x     = (const float*)d_in[0];
    const float* core0 = (const float*)d_in[1];
    const float* core1 = (const float*)d_in[2];
    const float* core2 = (const float*)d_in[3];
    const float* core3 = (const float*)d_in[4]; // bias
    float* out = (float*)d_out;

    dim3 grid(256 * 32);
    dim3 block(THREADS);
    tt_fused_f32<<<grid, block, 0, stream>>>(x, core0, core1, core2, core3, out);
}

// Round 2
// 608.077 us; speedup vs baseline: 4.5577x; 4.5577x over previous
//
#include <hip/hip_runtime.h>

// TT layer via bf16 MFMA (gfx950). Per WG: (b-pair, n1). 8 waves (512 thr).
//   Phase A: z1[r(16), m2, m3] = core0[n1]^T . x[b]      (MFMA, K=32)
//   Phase B: z2[(n2,s')(512), m3(32)] = A1[512,512] . z1  (MFMA, K=512)
//   Phase C: y[n2(32), n3(32)] = z2 . W2T^T + bias        (MFMA, K=512)
// Prepped in d_ws (bf16): A1[(n2*16+s')][(r*32+m2)] from core1,
//   A0T[n1*16+s][m1] from core0, W2T[n3][(s'*32+m3)] from core2.
// LDS: per local-b 32KB tile [32 rows][512 bf16], XOR-swizzled
//   (byte ^= (row&7)<<4); z2 overwrites z1 after a barrier.

typedef __attribute__((ext_vector_type(8))) short bf16x8;
typedef __attribute__((ext_vector_type(4))) float f32x4;

__device__ __forceinline__ unsigned short f2bf(float f) {
    union { float f; unsigned int u; } v; v.f = f;
    unsigned int u = v.u;
    u += 0x7fffu + ((u >> 16) & 1u);   // RNE (inputs finite)
    return (unsigned short)(u >> 16);
}

// ---------------- prep: transpose cores into bf16 MFMA layouts ----------------
// units of 8 output elems: A1 32768, A0T 2048, W2T 2048  -> 36864 units
__global__ void tt_prep(const float* __restrict__ core0,
                        const float* __restrict__ core1,
                        const float* __restrict__ core2,
                        unsigned short* __restrict__ ws)
{
    int u = blockIdx.x * 256 + threadIdx.x;
    unsigned short* A1  = ws;              // [512][512]
    unsigned short* A0T = ws + 262144;     // [512][32]
    unsigned short* W2T = ws + 278528;     // [32][512]
    bf16x8 o;
    if (u < 32768) {
        int e = u * 8;
        int row = e >> 9, cb = e & 511;
        int n2 = row >> 4, s = row & 15;
        int r = cb >> 5, m2b = cb & 31;
        const float* src = core1 + r * 16384 + n2 * 512 + m2b * 16 + s;
        #pragma unroll
        for (int j = 0; j < 8; ++j) o[j] = (short)f2bf(src[j * 16]);
        *(bf16x8*)(A1 + e) = o;
    } else if (u < 34816) {
        int e = (u - 32768) * 8;
        int row = e >> 5, m1b = e & 31;    // row = n1*16 + s
        int n1 = row >> 4, s = row & 15;
        const float* src = core0 + n1 * 512 + m1b * 16 + s;
        #pragma unroll
        for (int j = 0; j < 8; ++j) o[j] = (short)f2bf(src[j * 16]);
        *(bf16x8*)(A0T + e) = o;
    } else if (u < 36864) {
        int e = (u - 34816) * 8;
        int n3 = e >> 9, k = e & 511;
        int sp = k >> 5, m3b = k & 31;
        const float* src = core2 + sp * 1024 + n3 * 32 + m3b;
        #pragma unroll
        for (int j = 0; j < 8; ++j) o[j] = (short)f2bf(src[j]);
        *(bf16x8*)(W2T + e) = o;
    }
}

// ---------------- main fused kernel ----------------
__global__ __launch_bounds__(512, 4)
void tt_mfma(const float* __restrict__ x,
             const unsigned short* __restrict__ A1,
             const unsigned short* __restrict__ A0T,
             const unsigned short* __restrict__ W2T,
             const float* __restrict__ bias,
             float* __restrict__ out)
{
    __shared__ unsigned short smem[2 * 16384];   // 64 KB: [lb][32 rows][512]

    const int t   = threadIdx.x;
    const int l   = t & 63;
    const int w   = t >> 6;        // wave 0..7
    const int lb  = w >> 2;        // local b 0/1
    const int wq  = w & 3;         // 0..3
    const int l15 = l & 15;
    const int lg  = l >> 4;        // 0..3

    const int bp = blockIdx.x >> 5;
    const int n1 = blockIdx.x & 31;
    const int b  = bp * 2 + lb;

    char* zbase = (char*)smem + lb * 32768;

    // ---- Phase A: z1 tiles for p in [wq*256, wq*256+256) ----
    {
        bf16x8 afrag = *(const bf16x8*)(A0T + n1 * 512 + l15 * 32 + lg * 8);
        const float* xb = x + (size_t)b * 32768 + (lg * 8) * 1024;
        for (int pti = 0; pti < 16; ++pti) {
            int p = (wq * 16 + pti) * 16 + l15;
            bf16x8 bfrag;
            #pragma unroll
            for (int j = 0; j < 8; ++j) bfrag[j] = (short)f2bf(xb[j * 1024 + p]);
            f32x4 c = __builtin_amdgcn_mfma_f32_16x16x32_bf16(
                afrag, bfrag, (f32x4){0.f, 0.f, 0.f, 0.f}, 0, 0, 0);
            int m2 = p >> 5, m3 = p & 31;
            int rowbase = m3 << 10;
            int sw = (m3 & 7) << 4;
            #pragma unroll
            for (int i = 0; i < 4; ++i) {
                int r = lg * 4 + i;
                int k = r * 32 + m2;
                *(unsigned short*)(zbase + rowbase + ((k * 2) ^ sw)) = f2bf(c[i]);
            }
        }
    }
    __syncthreads();

    // ---- Phase B: C2[(n2,s'), m3] for n2 in [wq*8, wq*8+8) ----
    f32x4 acc[8][2];
    #pragma unroll
    for (int mt = 0; mt < 8; ++mt) {
        acc[mt][0] = (f32x4){0.f, 0.f, 0.f, 0.f};
        acc[mt][1] = (f32x4){0.f, 0.f, 0.f, 0.f};
    }
    {
        const int mtb = wq * 8;
        for (int ks = 0; ks < 16; ++ks) {
            int kb = ks * 64 + lg * 16;          // byte offset of k in row
            int r0 = l15, r1 = 16 + l15;
            bf16x8 b0 = *(const bf16x8*)(zbase + (r0 << 10) + (kb ^ ((r0 & 7) << 4)));
            bf16x8 b1 = *(const bf16x8*)(zbase + (r1 << 10) + (kb ^ ((r1 & 7) << 4)));
            const unsigned short* a1p = A1 + l15 * 512 + ks * 32 + lg * 8;
            #pragma unroll
            for (int mt = 0; mt < 8; ++mt) {
                bf16x8 af = *(const bf16x8*)(a1p + (mtb + mt) * 8192);
                acc[mt][0] = __builtin_amdgcn_mfma_f32_16x16x32_bf16(af, b0, acc[mt][0], 0, 0, 0);
                acc[mt][1] = __builtin_amdgcn_mfma_f32_16x16x32_bf16(af, b1, acc[mt][1], 0, 0, 0);
            }
        }
    }
    __syncthreads();   // all z1 reads complete

    // write z2 (bf16) over z1 space: row = n2, k = s'*32 + m3
    {
        #pragma unroll
        for (int mt = 0; mt < 8; ++mt) {
            int n2 = wq * 8 + mt;
            int rowbase = n2 << 10;
            int sw = (n2 & 7) << 4;
            #pragma unroll
            for (int nt = 0; nt < 2; ++nt) {
                int m3 = nt * 16 + l15;
                #pragma unroll
                for (int i = 0; i < 4; ++i) {
                    int sp = lg * 4 + i;
                    int k = sp * 32 + m3;
                    *(unsigned short*)(zbase + rowbase + ((k * 2) ^ sw)) =
                        f2bf(acc[mt][nt][i]);
                }
            }
        }
    }
    __syncthreads();

    // ---- Phase C: y[n2, n3] ; one 16x16 tile per wave ----
    {
        const int mt = (w >> 1) & 1;   // n2 tile
        const int nt = w & 1;          // n3 tile
        f32x4 c = (f32x4){0.f, 0.f, 0.f, 0.f};
        int row = mt * 16 + l15;
        int rb = (row << 10);
        int sw = (row & 7) << 4;
        const unsigned short* w2p = W2T + (nt * 16 + l15) * 512 + lg * 8;
        for (int ks = 0; ks < 16; ++ks) {
            int kb = ks * 64 + lg * 16;
            bf16x8 af = *(const bf16x8*)(zbase + rb + (kb ^ sw));
            bf16x8 bfg = *(const bf16x8*)(w2p + ks * 32);
            c = __builtin_amdgcn_mfma_f32_16x16x32_bf16(af, bfg, c, 0, 0, 0);
        }
        int n3 = nt * 16 + l15;
        size_t ob = (size_t)b * 32768 + (size_t)n1 * 1024;
        const float* bp2 = bias + n1 * 1024;
        #pragma unroll
        for (int i = 0; i < 4; ++i) {
            int n2 = mt * 16 + lg * 4 + i;
            out[ob + n2 * 32 + n3] = c[i] + bp2[n2 * 32 + n3];
        }
    }
}

extern "C" void kernel_launch(void* const* d_in, const int* in_sizes, int n_in,
                              void* d_out, int out_size, void* d_ws, size_t ws_size,
                              hipStream_t stream) {
    (void)in_sizes; (void)n_in; (void)out_size; (void)ws_size;
    const float* x     = (const float*)d_in[0];
    const float* core0 = (const float*)d_in[1];
    const float* core1 = (const float*)d_in[2];
    const float* core2 = (const float*)d_in[3];
    const float* bias  = (const float*)d_in[4];
    float* out = (float*)d_out;

    unsigned short* ws = (unsigned short*)d_ws;   // needs 576 KB
    unsigned short* A1  = ws;
    unsigned short* A0T = ws + 262144;
    unsigned short* W2T = ws + 278528;

    tt_prep<<<144, 256, 0, stream>>>(core0, core1, core2, ws);
    tt_mfma<<<4096, 512, 0, stream>>>(x, A1, A0T, W2T, bias, out);
}

// Round 3
// 374.413 us; speedup vs baseline: 7.4021x; 1.6241x over previous
//
#include <hip/hip_runtime.h>

// TT layer via bf16 MFMA (gfx950).
//   Phase A: z1[b][r,m2,m3] = core0[n1]^T . x[b]          (MFMA K=32)
//   Phase B: z2[b][(n2,s'),m3] = A1[512,512] . z1[512,32] (MFMA K=512, 4x4 tile/wave)
//   Phase C: y[b][n2,n3] = z2 . W2T^T + bias              (MFMA K=512)
// WG = (b-pair, n1), 8 waves. LDS: 2 x 32KB z-tile [32 rows][512 bf16],
// XOR-swizzled (byte ^= (row&7)<<4). z2 overwrites z1 after barrier.
// d_ws (bf16): A1[(n2*16+s')][(r*32+m2)], A0T[n1*16+s][m1], W2T[n3][(s'*32+m3)],
// and (if ws_size allows) xT[b][p][m1] so phase-A B-frags are 16B vector loads.

typedef __attribute__((ext_vector_type(8))) short bf16x8;
typedef __attribute__((ext_vector_type(4))) float f32x4;

#define WS_A1   0
#define WS_A0T  262144
#define WS_W2T  278528
#define WS_XT   294912
#define WS_XT_ELEMS 8388608
#define WS_NEED_BYTES ((size_t)(WS_XT + WS_XT_ELEMS) * 2)

__device__ __forceinline__ unsigned short f2bf(float f) {
    union { float f; unsigned int u; } v; v.f = f;
    unsigned int u = v.u;
    u += 0x7fffu + ((u >> 16) & 1u);   // RNE (inputs finite)
    return (unsigned short)(u >> 16);
}

// ---------------- prep: core transforms (+ optional x transpose) ----------------
template<bool XT>
__global__ void tt_prep(const float* __restrict__ x,
                        const float* __restrict__ core0,
                        const float* __restrict__ core1,
                        const float* __restrict__ core2,
                        unsigned short* __restrict__ ws)
{
    const int t = threadIdx.x;
    if (XT && blockIdx.x < 8192) {
        // transpose x[b][m1][m2*32+m3] (f32) -> xT[b][p=m2*32+m3][m1] (bf16)
        __shared__ float tile[32 * 37];
        const int b  = blockIdx.x >> 5;
        const int m2 = blockIdx.x & 31;
        {
            const int m1 = t >> 3, c4 = (t & 7) * 4;
            float4 v = *(const float4*)(x + (size_t)b * 32768 + m1 * 1024 + m2 * 32 + c4);
            *(float4*)&tile[m1 * 37 + c4] = v;  // 37*4B rows: 16B-aligned at c4%4==0? (m1*37+c4)%4 varies -> store scalars
        }
        __syncthreads();
        {
            const int m3 = t >> 3, g = t & 7;
            unsigned short o[4];
            #pragma unroll
            for (int j = 0; j < 4; ++j)
                o[j] = f2bf(tile[(g * 4 + j) * 37 + m3]);
            unsigned short* dst = ws + WS_XT + (size_t)b * 32768 + (m2 * 32 + m3) * 32 + g * 4;
            *(uint2*)dst = *(uint2*)o;
        }
        return;
    }
    const int u = (blockIdx.x - (XT ? 8192 : 0)) * 256 + t;
    unsigned short* A1  = ws + WS_A1;    // [512][512]
    unsigned short* A0T = ws + WS_A0T;   // [512][32]
    unsigned short* W2T = ws + WS_W2T;   // [32][512]
    bf16x8 o;
    if (u < 32768) {
        int e = u * 8;
        int row = e >> 9, cb = e & 511;
        int n2 = row >> 4, s = row & 15;
        int r = cb >> 5, m2b = cb & 31;
        const float* src = core1 + r * 16384 + n2 * 512 + m2b * 16 + s;
        #pragma unroll
        for (int j = 0; j < 8; ++j) o[j] = (short)f2bf(src[j * 16]);
        *(bf16x8*)(A1 + e) = o;
    } else if (u < 34816) {
        int e = (u - 32768) * 8;
        int row = e >> 5, m1b = e & 31;    // row = n1*16 + s
        int n1 = row >> 4, s = row & 15;
        const float* src = core0 + n1 * 512 + m1b * 16 + s;
        #pragma unroll
        for (int j = 0; j < 8; ++j) o[j] = (short)f2bf(src[j * 16]);
        *(bf16x8*)(A0T + e) = o;
    } else if (u < 36864) {
        int e = (u - 34816) * 8;
        int n3 = e >> 9, k = e & 511;
        int sp = k >> 5, m3b = k & 31;
        const float* src = core2 + sp * 1024 + n3 * 32 + m3b;
        #pragma unroll
        for (int j = 0; j < 8; ++j) o[j] = (short)f2bf(src[j]);
        *(bf16x8*)(W2T + e) = o;
    }
}

// ---------------- main fused kernel ----------------
template<bool XT>
__global__ __launch_bounds__(512, 4)
void tt_mfma(const float* __restrict__ x,
             const unsigned short* __restrict__ ws,
             const float* __restrict__ bias,
             float* __restrict__ out)
{
    __shared__ unsigned short smem[2 * 16384];   // 64 KB: [lb][32 rows][512]

    const unsigned short* A1  = ws + WS_A1;
    const unsigned short* A0T = ws + WS_A0T;
    const unsigned short* W2T = ws + WS_W2T;
    const unsigned short* xT  = ws + WS_XT;

    const int t   = threadIdx.x;
    const int l   = t & 63;
    const int w   = t >> 6;        // wave 0..7
    const int lb  = w >> 2;        // local b (phase A/C)
    const int wq  = w & 3;
    const int l15 = l & 15;
    const int lg  = l >> 4;        // 0..3

    const int bp = blockIdx.x >> 5;
    const int n1 = blockIdx.x & 31;
    const int b  = bp * 2 + lb;

    char* zme = (char*)smem + lb * 32768;

    // ---- Phase A: z1 tiles for p in [wq*256, wq*256+256) ----
    {
        bf16x8 afrag = *(const bf16x8*)(A0T + n1 * 512 + l15 * 32 + lg * 8);
        if (XT) {
            const unsigned short* xb = xT + (size_t)b * 32768 + lg * 8;
            #pragma unroll
            for (int pti = 0; pti < 16; ++pti) {
                int p = (wq * 16 + pti) * 16 + l15;
                bf16x8 bfrag = *(const bf16x8*)(xb + p * 32);
                f32x4 c = __builtin_amdgcn_mfma_f32_16x16x32_bf16(
                    afrag, bfrag, (f32x4){0.f, 0.f, 0.f, 0.f}, 0, 0, 0);
                int m2 = p >> 5, m3 = p & 31;
                int rowbase = m3 << 10;
                int sw = (m3 & 7) << 4;
                #pragma unroll
                for (int i = 0; i < 4; ++i) {
                    int k = (lg * 4 + i) * 32 + m2;
                    *(unsigned short*)(zme + rowbase + ((k * 2) ^ sw)) = f2bf(c[i]);
                }
            }
        } else {
            const float* xb = x + (size_t)b * 32768 + (lg * 8) * 1024;
            for (int pti = 0; pti < 16; ++pti) {
                int p = (wq * 16 + pti) * 16 + l15;
                bf16x8 bfrag;
                #pragma unroll
                for (int j = 0; j < 8; ++j) bfrag[j] = (short)f2bf(xb[j * 1024 + p]);
                f32x4 c = __builtin_amdgcn_mfma_f32_16x16x32_bf16(
                    afrag, bfrag, (f32x4){0.f, 0.f, 0.f, 0.f}, 0, 0, 0);
                int m2 = p >> 5, m3 = p & 31;
                int rowbase = m3 << 10;
                int sw = (m3 & 7) << 4;
                #pragma unroll
                for (int i = 0; i < 4; ++i) {
                    int k = (lg * 4 + i) * 32 + m2;
                    *(unsigned short*)(zme + rowbase + ((k * 2) ^ sw)) = f2bf(c[i]);
                }
            }
        }
    }
    __syncthreads();

    // ---- Phase B: wave w owns M rows [w*64, w*64+64), N = 64 (2 lb x 32 m3) ----
    f32x4 acc[4][4];
    #pragma unroll
    for (int mt = 0; mt < 4; ++mt)
        #pragma unroll
        for (int nt = 0; nt < 4; ++nt)
            acc[mt][nt] = (f32x4){0.f, 0.f, 0.f, 0.f};
    {
        const unsigned short* a1base = A1 + (w * 64 + l15) * 512 + lg * 8;
        char* z0 = (char*)smem;
        char* z1t = (char*)smem + 32768;
        const int rlo = l15, rhi = 16 + l15;
        const int sw = (l15 & 7) << 4;          // same for rlo/rhi
        for (int ks = 0; ks < 16; ++ks) {
            int kb = ks * 64 + lg * 16;
            int kofs = kb ^ sw;
            bf16x8 af0 = *(const bf16x8*)(a1base + ks * 32);
            bf16x8 af1 = *(const bf16x8*)(a1base + ks * 32 + 8192);
            bf16x8 af2 = *(const bf16x8*)(a1base + ks * 32 + 16384);
            bf16x8 af3 = *(const bf16x8*)(a1base + ks * 32 + 24576);
            bf16x8 bf0 = *(const bf16x8*)(z0  + (rlo << 10) + kofs);
            bf16x8 bf1 = *(const bf16x8*)(z0  + (rhi << 10) + kofs);
            bf16x8 bf2 = *(const bf16x8*)(z1t + (rlo << 10) + kofs);
            bf16x8 bf3 = *(const bf16x8*)(z1t + (rhi << 10) + kofs);
            acc[0][0] = __builtin_amdgcn_mfma_f32_16x16x32_bf16(af0, bf0, acc[0][0], 0, 0, 0);
            acc[0][1] = __builtin_amdgcn_mfma_f32_16x16x32_bf16(af0, bf1, acc[0][1], 0, 0, 0);
            acc[0][2] = __builtin_amdgcn_mfma_f32_16x16x32_bf16(af0, bf2, acc[0][2], 0, 0, 0);
            acc[0][3] = __builtin_amdgcn_mfma_f32_16x16x32_bf16(af0, bf3, acc[0][3], 0, 0, 0);
            acc[1][0] = __builtin_amdgcn_mfma_f32_16x16x32_bf16(af1, bf0, acc[1][0], 0, 0, 0);
            acc[1][1] = __builtin_amdgcn_mfma_f32_16x16x32_bf16(af1, bf1, acc[1][1], 0, 0, 0);
            acc[1][2] = __builtin_amdgcn_mfma_f32_16x16x32_bf16(af1, bf2, acc[1][2], 0, 0, 0);
            acc[1][3] = __builtin_amdgcn_mfma_f32_16x16x32_bf16(af1, bf3, acc[1][3], 0, 0, 0);
            acc[2][0] = __builtin_amdgcn_mfma_f32_16x16x32_bf16(af2, bf0, acc[2][0], 0, 0, 0);
            acc[2][1] = __builtin_amdgcn_mfma_f32_16x16x32_bf16(af2, bf1, acc[2][1], 0, 0, 0);
            acc[2][2] = __builtin_amdgcn_mfma_f32_16x16x32_bf16(af2, bf2, acc[2][2], 0, 0, 0);
            acc[2][3] = __builtin_amdgcn_mfma_f32_16x16x32_bf16(af2, bf3, acc[2][3], 0, 0, 0);
            acc[3][0] = __builtin_amdgcn_mfma_f32_16x16x32_bf16(af3, bf0, acc[3][0], 0, 0, 0);
            acc[3][1] = __builtin_amdgcn_mfma_f32_16x16x32_bf16(af3, bf1, acc[3][1], 0, 0, 0);
            acc[3][2] = __builtin_amdgcn_mfma_f32_16x16x32_bf16(af3, bf2, acc[3][2], 0, 0, 0);
            acc[3][3] = __builtin_amdgcn_mfma_f32_16x16x32_bf16(af3, bf3, acc[3][3], 0, 0, 0);
        }
    }
    __syncthreads();   // all z1 reads complete

    // write z2 (bf16): per lb tile, row = n2, k = s'*32 + m3
    {
        #pragma unroll
        for (int mt = 0; mt < 4; ++mt) {
            int n2 = w * 4 + mt;
            int rowbase = n2 << 10;
            int swz = (n2 & 7) << 4;
            #pragma unroll
            for (int nt = 0; nt < 4; ++nt) {
                char* zt = (char*)smem + (nt >> 1) * 32768;
                int m3 = (nt & 1) * 16 + l15;
                #pragma unroll
                for (int i = 0; i < 4; ++i) {
                    int k = (lg * 4 + i) * 32 + m3;
                    *(unsigned short*)(zt + rowbase + ((k * 2) ^ swz)) = f2bf(acc[mt][nt][i]);
                }
            }
        }
    }
    __syncthreads();

    // ---- Phase C: y[n2, n3]; wave -> (lb, n2-tile, n3-tile) ----
    {
        const int mt = (w >> 1) & 1;
        const int nt = w & 1;
        f32x4 c = (f32x4){0.f, 0.f, 0.f, 0.f};
        int row = mt * 16 + l15;
        int rb = row << 10;
        int swz = (row & 7) << 4;
        const unsigned short* w2p = W2T + (nt * 16 + l15) * 512 + lg * 8;
        for (int ks = 0; ks < 16; ++ks) {
            int kb = ks * 64 + lg * 16;
            bf16x8 af = *(const bf16x8*)(zme + rb + (kb ^ swz));
            bf16x8 bfg = *(const bf16x8*)(w2p + ks * 32);
            c = __builtin_amdgcn_mfma_f32_16x16x32_bf16(af, bfg, c, 0, 0, 0);
        }
        int n3 = nt * 16 + l15;
        size_t ob = (size_t)b * 32768 + (size_t)n1 * 1024;
        const float* bp2 = bias + n1 * 1024;
        #pragma unroll
        for (int i = 0; i < 4; ++i) {
            int n2 = mt * 16 + lg * 4 + i;
            out[ob + n2 * 32 + n3] = c[i] + bp2[n2 * 32 + n3];
        }
    }
}

extern "C" void kernel_launch(void* const* d_in, const int* in_sizes, int n_in,
                              void* d_out, int out_size, void* d_ws, size_t ws_size,
                              hipStream_t stream) {
    (void)in_sizes; (void)n_in; (void)out_size;
    const float* x     = (const float*)d_in[0];
    const float* core0 = (const float*)d_in[1];
    const float* core1 = (const float*)d_in[2];
    const float* core2 = (const float*)d_in[3];
    const float* bias  = (const float*)d_in[4];
    float* out = (float*)d_out;
    unsigned short* ws = (unsigned short*)d_ws;

    if (ws_size >= WS_NEED_BYTES) {
        tt_prep<true><<<8336, 256, 0, stream>>>(x, core0, core1, core2, ws);
        tt_mfma<true><<<4096, 512, 0, stream>>>(x, ws, bias, out);
    } else {
        tt_prep<false><<<144, 256, 0, stream>>>(x, core0, core1, core2, ws);
        tt_mfma<false><<<4096, 512, 0, stream>>>(x, ws, bias, out);
    }
}

// Round 4
// 221.884 us; speedup vs baseline: 12.4906x; 1.6874x over previous
//
#include <hip/hip_runtime.h>

// TT layer via bf16 MFMA (gfx950), NB=4 batches per WG.
//   Phase A: z1[b][m3][k'=m2*16+r]  = core0[n1]^T . x[b]       (MFMA K=32)
//   Phase B: z2[b][n2][k2=m3*16+s'] = A1[512,512] . z1         (MFMA, K=512)
//            8 waves x (M=64 rows, N=128 cols) -> acc[4][8], no A1 duplication
//   Phase C: y[b][n2,n3] = z2 . W2T^T + bias                   (MFMA K=512)
// WG = (b-quad, n1): 2048 WGs x 512 threads, 128KB dynamic LDS (4 x 32KB z-tile,
// XOR swizzle byte ^= (row&7)<<4; z2 overwrites z1 after barrier).
// d_ws (bf16): A1[(n2*16+s')][(m2*16+r)], A0T[(n1*16+s)][m1],
//              W2T[n3][(m3*16+s')], xT[b][p][m1].

typedef __attribute__((ext_vector_type(8))) short bf16x8;
typedef __attribute__((ext_vector_type(4))) float f32x4;

#define WS_A1   0
#define WS_A0T  262144
#define WS_W2T  278528
#define WS_XT   294912
#define WS_XT_ELEMS 8388608
#define WS_NEED_BYTES ((size_t)(WS_XT + WS_XT_ELEMS) * 2)

__device__ __forceinline__ unsigned short f2bf(float f) {
    union { float f; unsigned int u; } v; v.f = f;
    unsigned int u = v.u;
    u += 0x7fffu + ((u >> 16) & 1u);   // RNE (inputs finite)
    return (unsigned short)(u >> 16);
}

// ---------------- prep: core transforms (+ optional x transpose) ----------------
template<bool XT>
__global__ void tt_prep(const float* __restrict__ x,
                        const float* __restrict__ core0,
                        const float* __restrict__ core1,
                        const float* __restrict__ core2,
                        unsigned short* __restrict__ ws)
{
    const int t = threadIdx.x;
    if (XT && blockIdx.x < 8192) {
        // transpose x[b][m1][m2*32+m3] (f32) -> xT[b][p=m2*32+m3][m1] (bf16)
        __shared__ float tile[32 * 36];
        const int b  = blockIdx.x >> 5;
        const int m2 = blockIdx.x & 31;
        {
            const int m1 = t >> 3, c4 = (t & 7) * 4;
            float4 v = *(const float4*)(x + (size_t)b * 32768 + m1 * 1024 + m2 * 32 + c4);
            *(float4*)&tile[m1 * 36 + c4] = v;   // 36*4B stride keeps 16B alignment
        }
        __syncthreads();
        {
            const int m3 = t >> 3, g = t & 7;
            unsigned short o[4];
            #pragma unroll
            for (int j = 0; j < 4; ++j)
                o[j] = f2bf(tile[(g * 4 + j) * 36 + m3]);
            unsigned short* dst = ws + WS_XT + (size_t)b * 32768 + (m2 * 32 + m3) * 32 + g * 4;
            *(uint2*)dst = *(uint2*)o;
        }
        return;
    }
    const int u = (blockIdx.x - (XT ? 8192 : 0)) * 256 + t;
    unsigned short* A1  = ws + WS_A1;    // [512 rows=(n2*16+s')][512 cols=(m2*16+r)]
    unsigned short* A0T = ws + WS_A0T;   // [512 rows=(n1*16+s)][32 m1]
    unsigned short* W2T = ws + WS_W2T;   // [32 n3][512 k2=(m3*16+s')]
    bf16x8 o;
    if (u < 32768) {
        int e = u * 8;
        int row = e >> 9, col0 = e & 511;
        int n2 = row >> 4, s = row & 15;
        int m2 = col0 >> 4, r0 = col0 & 15;   // r0 in {0,8}
        const float* src = core1 + n2 * 512 + m2 * 16 + s;
        #pragma unroll
        for (int j = 0; j < 8; ++j) o[j] = (short)f2bf(src[(r0 + j) * 16384]);
        *(bf16x8*)(A1 + e) = o;
    } else if (u < 34816) {
        int e = (u - 32768) * 8;
        int row = e >> 5, m1b = e & 31;    // row = n1*16 + s
        int n1 = row >> 4, s = row & 15;
        const float* src = core0 + n1 * 512 + m1b * 16 + s;
        #pragma unroll
        for (int j = 0; j < 8; ++j) o[j] = (short)f2bf(src[j * 16]);
        *(bf16x8*)(A0T + e) = o;
    } else if (u < 36864) {
        int e = (u - 34816) * 8;
        int n3 = e >> 9, k20 = e & 511;
        int m3 = k20 >> 4, s0 = k20 & 15;  // s0 in {0,8}
        const float* src = core2 + n3 * 32 + m3;
        #pragma unroll
        for (int j = 0; j < 8; ++j) o[j] = (short)f2bf(src[(s0 + j) * 1024]);
        *(bf16x8*)(W2T + e) = o;
    }
}

// ---------------- main fused kernel ----------------
template<bool XT>
__global__ __launch_bounds__(512, 2)
void tt_mfma(const float* __restrict__ x,
             const unsigned short* __restrict__ ws,
             const float* __restrict__ bias,
             float* __restrict__ out)
{
    extern __shared__ char smem[];   // 4 x 32KB: z-tile per local b

    const unsigned short* A1  = ws + WS_A1;
    const unsigned short* A0T = ws + WS_A0T;
    const unsigned short* W2T = ws + WS_W2T;
    const unsigned short* xT  = ws + WS_XT;

    const int t   = threadIdx.x;
    const int l   = t & 63;
    const int w   = t >> 6;        // wave 0..7
    const int l15 = l & 15;
    const int lg  = l >> 4;        // 0..3

    const int bq = blockIdx.x >> 5;
    const int n1 = blockIdx.x & 31;

    // ---- Phase A: wave -> (lb = w>>1, p-half = w&1); 32 MFMAs ----
    {
        const int lb = w >> 1, ph = w & 1;
        const int b  = bq * 4 + lb;
        char* zb = smem + lb * 32768;
        bf16x8 afrag = *(const bf16x8*)(A0T + n1 * 512 + l15 * 32 + lg * 8);
        if (XT) {
            const unsigned short* xb = xT + (size_t)b * 32768 + lg * 8;
            #pragma unroll 4
            for (int pti = 0; pti < 32; ++pti) {
                int p = ph * 512 + pti * 16 + l15;
                bf16x8 bfrag = *(const bf16x8*)(xb + p * 32);
                f32x4 c = __builtin_amdgcn_mfma_f32_16x16x32_bf16(
                    afrag, bfrag, (f32x4){0.f, 0.f, 0.f, 0.f}, 0, 0, 0);
                int m2 = p >> 5, m3 = p & 31;
                unsigned short h[4];
                #pragma unroll
                for (int i = 0; i < 4; ++i) h[i] = f2bf(c[i]);
                int off = (m3 << 10) + (((m2 * 32 + lg * 8)) ^ ((m3 & 7) << 4));
                *(uint2*)(zb + off) = *(uint2*)h;
            }
        } else {
            const float* xb = x + (size_t)b * 32768 + (lg * 8) * 1024;
            for (int pti = 0; pti < 32; ++pti) {
                int p = ph * 512 + pti * 16 + l15;
                bf16x8 bfrag;
                #pragma unroll
                for (int j = 0; j < 8; ++j) bfrag[j] = (short)f2bf(xb[j * 1024 + p]);
                f32x4 c = __builtin_amdgcn_mfma_f32_16x16x32_bf16(
                    afrag, bfrag, (f32x4){0.f, 0.f, 0.f, 0.f}, 0, 0, 0);
                int m2 = p >> 5, m3 = p & 31;
                unsigned short h[4];
                #pragma unroll
                for (int i = 0; i < 4; ++i) h[i] = f2bf(c[i]);
                int off = (m3 << 10) + (((m2 * 32 + lg * 8)) ^ ((m3 & 7) << 4));
                *(uint2*)(zb + off) = *(uint2*)h;
            }
        }
    }
    __syncthreads();

    // ---- Phase B: wave w owns M rows [w*64, w*64+64); N = 128 (4 b x 32 m3) ----
    f32x4 acc[4][8];
    #pragma unroll
    for (int mt = 0; mt < 4; ++mt)
        #pragma unroll
        for (int nt = 0; nt < 8; ++nt)
            acc[mt][nt] = (f32x4){0.f, 0.f, 0.f, 0.f};
    {
        const unsigned short* a1p = A1 + (w * 64 + l15) * 512 + lg * 8;
        const int rsw = ((l15 & 7) << 4);
        #pragma unroll 2
        for (int ks = 0; ks < 16; ++ks) {
            int kb = ks * 64 + lg * 16;
            bf16x8 af[4];
            #pragma unroll
            for (int mt = 0; mt < 4; ++mt)
                af[mt] = *(const bf16x8*)(a1p + mt * 8192 + ks * 32);
            bf16x8 bf[8];
            #pragma unroll
            for (int b4 = 0; b4 < 4; ++b4) {
                char* zb = smem + b4 * 32768;
                int r0 = l15, r1 = 16 + l15;
                bf[b4 * 2 + 0] = *(const bf16x8*)(zb + (r0 << 10) + (kb ^ rsw));
                bf[b4 * 2 + 1] = *(const bf16x8*)(zb + (r1 << 10) + (kb ^ rsw));
            }
            #pragma unroll
            for (int mt = 0; mt < 4; ++mt)
                #pragma unroll
                for (int nt = 0; nt < 8; ++nt)
                    acc[mt][nt] = __builtin_amdgcn_mfma_f32_16x16x32_bf16(
                        af[mt], bf[nt], acc[mt][nt], 0, 0, 0);
        }
    }
    __syncthreads();   // all z1 reads complete

    // write z2 (bf16): z2[b][n2 row][k2 = m3*16 + s'], s' = lg*4+i -> b64 stores
    {
        #pragma unroll
        for (int mt = 0; mt < 4; ++mt) {
            int n2 = w * 4 + mt;
            int rowbase = n2 << 10;
            int swz = (n2 & 7) << 4;
            #pragma unroll
            for (int nt = 0; nt < 8; ++nt) {
                char* zb = smem + (nt >> 1) * 32768;
                int m3 = (nt & 1) * 16 + l15;
                unsigned short h[4];
                #pragma unroll
                for (int i = 0; i < 4; ++i) h[i] = f2bf(acc[mt][nt][i]);
                int off = rowbase + ((m3 * 32 + lg * 8) ^ swz);
                *(uint2*)(zb + off) = *(uint2*)h;
            }
        }
    }
    __syncthreads();

    // ---- Phase C: wave -> (lb = w>>1, n3-half = w&1); y = z2 . W2T^T + bias ----
    {
        const int lb = w >> 1, n3h = w & 1;
        const int b  = bq * 4 + lb;
        char* zb = smem + lb * 32768;
        f32x4 c[2];
        c[0] = (f32x4){0.f, 0.f, 0.f, 0.f};
        c[1] = (f32x4){0.f, 0.f, 0.f, 0.f};
        const unsigned short* w2p = W2T + (n3h * 16 + l15) * 512 + lg * 8;
        #pragma unroll 2
        for (int ks = 0; ks < 16; ++ks) {
            bf16x8 bfg = *(const bf16x8*)(w2p + ks * 32);
            #pragma unroll
            for (int mt = 0; mt < 2; ++mt) {
                int row = mt * 16 + l15;   // n2 local
                bf16x8 af = *(const bf16x8*)(zb + (row << 10) +
                                             ((ks * 64 + lg * 16) ^ ((row & 7) << 4)));
                c[mt] = __builtin_amdgcn_mfma_f32_16x16x32_bf16(af, bfg, c[mt], 0, 0, 0);
            }
        }
        int n3 = n3h * 16 + l15;
        size_t ob = (size_t)b * 32768 + (size_t)n1 * 1024;
        const float* bp2 = bias + n1 * 1024;
        #pragma unroll
        for (int mt = 0; mt < 2; ++mt)
            #pragma unroll
            for (int i = 0; i < 4; ++i) {
                int n2 = mt * 16 + lg * 4 + i;
                out[ob + n2 * 32 + n3] = c[mt][i] + bp2[n2 * 32 + n3];
            }
    }
}

extern "C" void kernel_launch(void* const* d_in, const int* in_sizes, int n_in,
                              void* d_out, int out_size, void* d_ws, size_t ws_size,
                              hipStream_t stream) {
    (void)in_sizes; (void)n_in; (void)out_size;
    const float* x     = (const float*)d_in[0];
    const float* core0 = (const float*)d_in[1];
    const float* core1 = (const float*)d_in[2];
    const float* core2 = (const float*)d_in[3];
    const float* bias  = (const float*)d_in[4];
    float* out = (float*)d_out;
    unsigned short* ws = (unsigned short*)d_ws;

    const int lds_bytes = 4 * 32768;   // 128 KB
    if (ws_size >= WS_NEED_BYTES) {
        hipFuncSetAttribute((const void*)tt_mfma<true>,
                            hipFuncAttributeMaxDynamicSharedMemorySize, lds_bytes);
        tt_prep<true><<<8336, 256, 0, stream>>>(x, core0, core1, core2, ws);
        tt_mfma<true><<<2048, 512, lds_bytes, stream>>>(x, ws, bias, out);
    } else {
        hipFuncSetAttribute((const void*)tt_mfma<false>,
                            hipFuncAttributeMaxDynamicSharedMemorySize, lds_bytes);
        tt_prep<false><<<144, 256, 0, stream>>>(x, core0, core1, core2, ws);
        tt_mfma<false><<<2048, 512, lds_bytes, stream>>>(x, ws, bias, out);
    }
}

// Round 5
// 221.660 us; speedup vs baseline: 12.5032x; 1.0010x over previous
//
#include <hip/hip_runtime.h>

// TT layer via bf16 MFMA (gfx950), NB=4 batches per WG, reg-pipelined.
//   Phase A: z1[b][m3][k'=m2*16+r]  = core0[n1]^T . x[b]       (MFMA K=32)
//   Phase B: z2[b][n2][k2=m3*16+s'] = A1[512,512] . z1         (MFMA, K=512)
//            8 waves x (M=64 rows, N=128 cols) -> acc[4][8]
//   Phase C: y[b][n2,n3] = z2 . W2T^T + bias                   (MFMA K=512)
// WG = (b-quad, n1): 2048 WGs x 512 threads, 128KB dynamic LDS (4 x 32KB z-tile,
// XOR swizzle byte ^= (row&7)<<4; z2 overwrites z1 after barrier).
// XCD-swizzled blockIdx: each XCD owns 8 bq's (2MB xT + 512KB A1 L2-resident).
// d_ws (bf16): A1[(n2*16+s')][(m2*16+r)], A0T[(n1*16+s)][m1],
//              W2T[n3][(m3*16+s')], xT[b][p][m1].

typedef __attribute__((ext_vector_type(8))) short bf16x8;
typedef __attribute__((ext_vector_type(4))) float f32x4;

#define WS_A1   0
#define WS_A0T  262144
#define WS_W2T  278528
#define WS_XT   294912
#define WS_XT_ELEMS 8388608
#define WS_NEED_BYTES ((size_t)(WS_XT + WS_XT_ELEMS) * 2)

__device__ __forceinline__ unsigned short f2bf(float f) {
    union { float f; unsigned int u; } v; v.f = f;
    unsigned int u = v.u;
    u += 0x7fffu + ((u >> 16) & 1u);   // RNE (inputs finite)
    return (unsigned short)(u >> 16);
}

// ---------------- prep: core transforms (+ optional x transpose) ----------------
template<bool XT>
__global__ void tt_prep(const float* __restrict__ x,
                        const float* __restrict__ core0,
                        const float* __restrict__ core1,
                        const float* __restrict__ core2,
                        unsigned short* __restrict__ ws)
{
    const int t = threadIdx.x;
    if (XT && blockIdx.x < 8192) {
        // transpose x[b][m1][m2*32+m3] (f32) -> xT[b][p=m2*32+m3][m1] (bf16)
        __shared__ float tile[32 * 36];
        const int b  = blockIdx.x >> 5;
        const int m2 = blockIdx.x & 31;
        {
            const int m1 = t >> 3, c4 = (t & 7) * 4;
            float4 v = *(const float4*)(x + (size_t)b * 32768 + m1 * 1024 + m2 * 32 + c4);
            *(float4*)&tile[m1 * 36 + c4] = v;
        }
        __syncthreads();
        {
            const int m3 = t >> 3, g = t & 7;
            unsigned short o[4];
            #pragma unroll
            for (int j = 0; j < 4; ++j)
                o[j] = f2bf(tile[(g * 4 + j) * 36 + m3]);
            unsigned short* dst = ws + WS_XT + (size_t)b * 32768 + (m2 * 32 + m3) * 32 + g * 4;
            *(uint2*)dst = *(uint2*)o;
        }
        return;
    }
    const int u = (blockIdx.x - (XT ? 8192 : 0)) * 256 + t;
    unsigned short* A1  = ws + WS_A1;    // [512 rows=(n2*16+s')][512 cols=(m2*16+r)]
    unsigned short* A0T = ws + WS_A0T;   // [512 rows=(n1*16+s)][32 m1]
    unsigned short* W2T = ws + WS_W2T;   // [32 n3][512 k2=(m3*16+s')]
    bf16x8 o;
    if (u < 32768) {
        int e = u * 8;
        int row = e >> 9, col0 = e & 511;
        int n2 = row >> 4, s = row & 15;
        int m2 = col0 >> 4, r0 = col0 & 15;   // r0 in {0,8}
        const float* src = core1 + n2 * 512 + m2 * 16 + s;
        #pragma unroll
        for (int j = 0; j < 8; ++j) o[j] = (short)f2bf(src[(r0 + j) * 16384]);
        *(bf16x8*)(A1 + e) = o;
    } else if (u < 34816) {
        int e = (u - 32768) * 8;
        int row = e >> 5, m1b = e & 31;    // row = n1*16 + s
        int n1 = row >> 4, s = row & 15;
        const float* src = core0 + n1 * 512 + m1b * 16 + s;
        #pragma unroll
        for (int j = 0; j < 8; ++j) o[j] = (short)f2bf(src[j * 16]);
        *(bf16x8*)(A0T + e) = o;
    } else if (u < 36864) {
        int e = (u - 34816) * 8;
        int n3 = e >> 9, k20 = e & 511;
        int m3 = k20 >> 4, s0 = k20 & 15;  // s0 in {0,8}
        const float* src = core2 + n3 * 32 + m3;
        #pragma unroll
        for (int j = 0; j < 8; ++j) o[j] = (short)f2bf(src[(s0 + j) * 1024]);
        *(bf16x8*)(W2T + e) = o;
    }
}

// ---------------- main fused kernel ----------------
template<bool XT>
__global__ __launch_bounds__(512, 2)
void tt_mfma(const float* __restrict__ x,
             const unsigned short* __restrict__ ws,
             const float* __restrict__ bias,
             float* __restrict__ out)
{
    extern __shared__ char smem[];   // 4 x 32KB: z-tile per local b

    const unsigned short* A1  = ws + WS_A1;
    const unsigned short* A0T = ws + WS_A0T;
    const unsigned short* W2T = ws + WS_W2T;
    const unsigned short* xT  = ws + WS_XT;

    const int t   = threadIdx.x;
    const int l   = t & 63;
    const int w   = t >> 6;        // wave 0..7
    const int l15 = l & 15;
    const int lg  = l >> 4;        // 0..3

    // XCD-aware bijective swizzle: 2048 WGs, 8 XCDs, 256 per XCD.
    const int swzid = (blockIdx.x & 7) * 256 + (blockIdx.x >> 3);
    const int bq = swzid >> 5;
    const int n1 = swzid & 31;

    // ---- Phase A: wave -> (lb = w>>1, p-half = w&1); 32 MFMAs, dbuf'd ----
    {
        const int lb = w >> 1, ph = w & 1;
        const int b  = bq * 4 + lb;
        char* zb = smem + lb * 32768;
        bf16x8 afrag = *(const bf16x8*)(A0T + n1 * 512 + l15 * 32 + lg * 8);
        if (XT) {
            const unsigned short* xb = xT + (size_t)b * 32768 + lg * 8;
            bf16x8 bfrag[2];
            bfrag[0] = *(const bf16x8*)(xb + (ph * 512 + l15) * 32);
            #pragma unroll
            for (int pti = 0; pti < 32; ++pti) {
                if (pti < 31) {
                    int pn = ph * 512 + (pti + 1) * 16 + l15;
                    bfrag[(pti + 1) & 1] = *(const bf16x8*)(xb + pn * 32);
                }
                int p = ph * 512 + pti * 16 + l15;
                f32x4 c = __builtin_amdgcn_mfma_f32_16x16x32_bf16(
                    afrag, bfrag[pti & 1], (f32x4){0.f, 0.f, 0.f, 0.f}, 0, 0, 0);
                int m2 = p >> 5, m3 = p & 31;
                unsigned short h[4];
                #pragma unroll
                for (int i = 0; i < 4; ++i) h[i] = f2bf(c[i]);
                int off = (m3 << 10) + (((m2 * 32 + lg * 8)) ^ ((m3 & 7) << 4));
                *(uint2*)(zb + off) = *(uint2*)h;
            }
        } else {
            const float* xb = x + (size_t)b * 32768 + (lg * 8) * 1024;
            for (int pti = 0; pti < 32; ++pti) {
                int p = ph * 512 + pti * 16 + l15;
                bf16x8 bfrag;
                #pragma unroll
                for (int j = 0; j < 8; ++j) bfrag[j] = (short)f2bf(xb[j * 1024 + p]);
                f32x4 c = __builtin_amdgcn_mfma_f32_16x16x32_bf16(
                    afrag, bfrag, (f32x4){0.f, 0.f, 0.f, 0.f}, 0, 0, 0);
                int m2 = p >> 5, m3 = p & 31;
                unsigned short h[4];
                #pragma unroll
                for (int i = 0; i < 4; ++i) h[i] = f2bf(c[i]);
                int off = (m3 << 10) + (((m2 * 32 + lg * 8)) ^ ((m3 & 7) << 4));
                *(uint2*)(zb + off) = *(uint2*)h;
            }
        }
    }
    __syncthreads();

    // ---- Phase B: wave w owns M rows [w*64, w*64+64); N = 128 (4 b x 32 m3) ----
    // Register-pipelined: prefetch ks+1 operands during ks MFMAs.
    f32x4 acc[4][8];
    #pragma unroll
    for (int mt = 0; mt < 4; ++mt)
        #pragma unroll
        for (int nt = 0; nt < 8; ++nt)
            acc[mt][nt] = (f32x4){0.f, 0.f, 0.f, 0.f};
    {
        const unsigned short* a1p = A1 + (w * 64 + l15) * 512 + lg * 8;
        const int rsw = ((l15 & 7) << 4);
        const int rlo = l15 << 10, rhi = (16 + l15) << 10;

        bf16x8 af[2][4], bf[2][8];
        // prologue: ks = 0 operands
        #pragma unroll
        for (int mt = 0; mt < 4; ++mt)
            af[0][mt] = *(const bf16x8*)(a1p + mt * 8192);
        {
            int kofs = (lg * 16) ^ rsw;
            #pragma unroll
            for (int b4 = 0; b4 < 4; ++b4) {
                char* zb = smem + b4 * 32768;
                bf[0][b4 * 2 + 0] = *(const bf16x8*)(zb + rlo + kofs);
                bf[0][b4 * 2 + 1] = *(const bf16x8*)(zb + rhi + kofs);
            }
        }
        #pragma unroll
        for (int ks = 0; ks < 16; ++ks) {
            const int cur = ks & 1, nxt = cur ^ 1;
            if (ks < 15) {
                int kb = (ks + 1) * 64 + lg * 16;
                int kofs = kb ^ rsw;
                #pragma unroll
                for (int mt = 0; mt < 4; ++mt)
                    af[nxt][mt] = *(const bf16x8*)(a1p + mt * 8192 + (ks + 1) * 32);
                #pragma unroll
                for (int b4 = 0; b4 < 4; ++b4) {
                    char* zb = smem + b4 * 32768;
                    bf[nxt][b4 * 2 + 0] = *(const bf16x8*)(zb + rlo + kofs);
                    bf[nxt][b4 * 2 + 1] = *(const bf16x8*)(zb + rhi + kofs);
                }
            }
            #pragma unroll
            for (int mt = 0; mt < 4; ++mt)
                #pragma unroll
                for (int nt = 0; nt < 8; ++nt)
                    acc[mt][nt] = __builtin_amdgcn_mfma_f32_16x16x32_bf16(
                        af[cur][mt], bf[cur][nt], acc[mt][nt], 0, 0, 0);
        }
    }
    __syncthreads();   // all z1 reads complete

    // write z2 (bf16): z2[b][n2 row][k2 = m3*16 + s'], s' = lg*4+i -> b64 stores
    {
        #pragma unroll
        for (int mt = 0; mt < 4; ++mt) {
            int n2 = w * 4 + mt;
            int rowbase = n2 << 10;
            int swz = (n2 & 7) << 4;
            #pragma unroll
            for (int nt = 0; nt < 8; ++nt) {
                char* zb = smem + (nt >> 1) * 32768;
                int m3 = (nt & 1) * 16 + l15;
                unsigned short h[4];
                #pragma unroll
                for (int i = 0; i < 4; ++i) h[i] = f2bf(acc[mt][nt][i]);
                int off = rowbase + ((m3 * 32 + lg * 8) ^ swz);
                *(uint2*)(zb + off) = *(uint2*)h;
            }
        }
    }
    __syncthreads();

    // ---- Phase C: wave -> (lb = w>>1, n3-half = w&1); y = z2 . W2T^T + bias ----
    {
        const int lb = w >> 1, n3h = w & 1;
        const int b  = bq * 4 + lb;
        char* zb = smem + lb * 32768;
        f32x4 c[2];
        c[0] = (f32x4){0.f, 0.f, 0.f, 0.f};
        c[1] = (f32x4){0.f, 0.f, 0.f, 0.f};
        const unsigned short* w2p = W2T + (n3h * 16 + l15) * 512 + lg * 8;
        bf16x8 bfg[2];
        bfg[0] = *(const bf16x8*)(w2p);
        #pragma unroll
        for (int ks = 0; ks < 16; ++ks) {
            if (ks < 15) bfg[(ks + 1) & 1] = *(const bf16x8*)(w2p + (ks + 1) * 32);
            #pragma unroll
            for (int mt = 0; mt < 2; ++mt) {
                int row = mt * 16 + l15;   // n2 local
                bf16x8 af = *(const bf16x8*)(zb + (row << 10) +
                                             ((ks * 64 + lg * 16) ^ ((row & 7) << 4)));
                c[mt] = __builtin_amdgcn_mfma_f32_16x16x32_bf16(af, bfg[ks & 1], c[mt], 0, 0, 0);
            }
        }
        int n3 = n3h * 16 + l15;
        size_t ob = (size_t)b * 32768 + (size_t)n1 * 1024;
        const float* bp2 = bias + n1 * 1024;
        #pragma unroll
        for (int mt = 0; mt < 2; ++mt)
            #pragma unroll
            for (int i = 0; i < 4; ++i) {
                int n2 = mt * 16 + lg * 4 + i;
                out[ob + n2 * 32 + n3] = c[mt][i] + bp2[n2 * 32 + n3];
            }
    }
}

extern "C" void kernel_launch(void* const* d_in, const int* in_sizes, int n_in,
                              void* d_out, int out_size, void* d_ws, size_t ws_size,
                              hipStream_t stream) {
    (void)in_sizes; (void)n_in; (void)out_size;
    const float* x     = (const float*)d_in[0];
    const float* core0 = (const float*)d_in[1];
    const float* core1 = (const float*)d_in[2];
    const float* core2 = (const float*)d_in[3];
    const float* bias  = (const float*)d_in[4];
    float* out = (float*)d_out;
    unsigned short* ws = (unsigned short*)d_ws;

    const int lds_bytes = 4 * 32768;   // 128 KB
    if (ws_size >= WS_NEED_BYTES) {
        hipFuncSetAttribute((const void*)tt_mfma<true>,
                            hipFuncAttributeMaxDynamicSharedMemorySize, lds_bytes);
        tt_prep<true><<<8336, 256, 0, stream>>>(x, core0, core1, core2, ws);
        tt_mfma<true><<<2048, 512, lds_bytes, stream>>>(x, ws, bias, out);
    } else {
        hipFuncSetAttribute((const void*)tt_mfma<false>,
                            hipFuncAttributeMaxDynamicSharedMemorySize, lds_bytes);
        tt_prep<false><<<144, 256, 0, stream>>>(x, core0, core1, core2, ws);
        tt_mfma<false><<<2048, 512, lds_bytes, stream>>>(x, ws, bias, out);
    }
}